// Round 14
// baseline (94.717 us; speedup 1.0000x reference)
//
#include <hip/hip_runtime.h>
#include <math.h>

// ChamferLoss: pc_src [B,3,M] f32, pc_dst [B,3,N] f32 -> scalar mean over (B,M)
// of min_n ||src_m - dst_n||.
//
// MFMA engine: d2p(n,m) = |d_n|^2 - 2 s_m . d_n as ONE K-column of
// v_mfma_f32_32x32x16_f16, split-f16 precision (per coord uh*sh, uh*sl,
// ul*sh with u=-2d; plus (wh,wl)*1; 11/16 K-slots; absmax 0.0 since R11).
//
// R13 -> R14: single real dispatch. finish fused via per-group last-arrival
// folder: the 16 blocks sharing (b,srcgrp) tick tg[group] (acq_rel, agent);
// the 16th folds the group's 16x512 partials (agent-scope atomic loads; the
// partials were agent-scope atomic stores + threadfence -> cross-XCD safe per
// G16), computes sqrt+sum, fixed-point atomicAdd + global ticket; last of 64
// folders writes the scalar. Only extra dispatch: 272-byte memset for ctrl.

#define TPB 256

constexpr int NB = 4;
constexpr int NM = 8192;
constexpr int NN = 8192;
constexpr int NPTS = NB * NM;                     // 32768
constexpr int NSEG = 16;                          // dst segments
constexpr int DSEG = NN / NSEG;                   // 512 dst per segment
constexpr int TILES = DSEG / 32;                  // 16 MFMA tiles
constexpr int NSRCG = NM / 512;                   // 16 src groups (512 cols)
constexpr int NGRP = NB * NSRCG;                  // 64 (b,srcgrp) groups

typedef _Float16 half8 __attribute__((ext_vector_type(8)));
typedef float f32x16 __attribute__((ext_vector_type(16)));

__device__ __forceinline__ float min3(float a, float b, float c) {
    return fminf(fminf(a, b), c);                 // -> v_min3_f32
}
__device__ __forceinline__ float tile_min(const f32x16& c, float acc) {
    float v0 = min3(c[0],  c[1],  c[2]);
    float v1 = min3(c[3],  c[4],  c[5]);
    float v2 = min3(c[6],  c[7],  c[8]);
    float v3 = min3(c[9],  c[10], c[11]);
    float v4 = min3(c[12], c[13], c[14]);
    float w0 = min3(v0, v1, c[15]);
    float w1 = min3(v2, v3, v4);
    return min3(acc, w0, w1);
}
// LDS A-frag slot for (row r, half h), 16B granules, XOR-swizzled.
__device__ __forceinline__ int aidx(int r, int h) {
    return ((r << 1) | h) ^ ((r >> 2) & 7);
}

// Fused kernel. Block = (sg, b, srcgrp). Phase A: build A-frags in LDS +
// B-frags in regs, 16 tiles x {ds_read, 4 MFMA, 4 min-trees}, store partial
// min (agent atomic stores). Phase B (16th arrival per group only): fold
// 16 partials/col, sqrt, block-sum, fixed-point accumulate, ticket writeout.
__global__ __launch_bounds__(TPB) void fused_kernel(const float* __restrict__ src,
                                                    const float* __restrict__ dst,
                                                    float* __restrict__ part,
                                                    unsigned* __restrict__ tg,
                                                    unsigned long long* __restrict__ sumfix,
                                                    unsigned* __restrict__ ticket,
                                                    float* __restrict__ out) {
    __shared__ uint4 alds[DSEG * 2];              // 16 KB
    __shared__ int sfold;
    __shared__ float wsum[4];

    int l  = threadIdx.x & 63;
    int wv = threadIdx.x >> 6;
    int sg = blockIdx.x & (NSEG - 1);
    int b  = (blockIdx.x >> 4) & 3;
    int srcgrp = blockIdx.x >> 6;                 // 0..15

    // ---- Phase 1a: A-frags (dst) -> LDS, 2 rows per thread ----
    const float* pd = dst + (size_t)b * 3 * NN;
#pragma unroll
    for (int rr = 0; rr < 2; ++rr) {
        int r = threadIdx.x + rr * TPB;           // row in segment
        int n = sg * DSEG + r;
        float x = pd[n], y = pd[NN + n], z = pd[2 * NN + n];
        float ux = -2.0f * x, uy = -2.0f * y, uz = -2.0f * z;
        float w = fmaf(x, x, fmaf(y, y, z * z));
        _Float16 uhx = (_Float16)ux; _Float16 ulx = (_Float16)(ux - (float)uhx);
        _Float16 uhy = (_Float16)uy; _Float16 uly = (_Float16)(uy - (float)uhy);
        _Float16 uhz = (_Float16)uz; _Float16 ulz = (_Float16)(uz - (float)uhz);
        _Float16 wh  = (_Float16)w;  _Float16 wl  = (_Float16)(w - (float)wh);
        half8 a0 = {uhx, uhx, ulx, uhy, uhy, uly, uhz, uhz};
        half8 a1 = {ulz, wh, wl, (_Float16)0.f, (_Float16)0.f,
                    (_Float16)0.f, (_Float16)0.f, (_Float16)0.f};
        alds[aidx(r, 0)] = *(uint4*)&a0;
        alds[aidx(r, 1)] = *(uint4*)&a1;
    }

    // ---- Phase 1b: B-frags (src) in regs, 4 cols per lane ----
    int mbase = (srcgrp * 4 + wv) * 128;          // wave's 128 src cols
    int lg = l & 31;
    int hi = l >> 5;                              // 0: K0-7, 1: K8-15
    const float* ps = src + (size_t)b * 3 * NM;
    half8 bf[4];
#pragma unroll
    for (int k = 0; k < 4; ++k) {
        int c = mbase + k * 32 + lg;
        float x = ps[c], y = ps[NM + c], z = ps[2 * NM + c];
        _Float16 shx = (_Float16)x; _Float16 slx = (_Float16)(x - (float)shx);
        _Float16 shy = (_Float16)y; _Float16 sly = (_Float16)(y - (float)shy);
        _Float16 shz = (_Float16)z; _Float16 slz = (_Float16)(z - (float)shz);
        half8 b0 = {shx, slx, shx, shy, sly, shy, shz, slz};
        half8 b1 = {shz, (_Float16)1.f, (_Float16)1.f, (_Float16)0.f,
                    (_Float16)0.f, (_Float16)0.f, (_Float16)0.f, (_Float16)0.f};
        bf[k] = hi ? b1 : b0;
    }
    __syncthreads();

    // ---- Phase 2: MFMA main loop ----
    const f32x16 zc = {0.f,0.f,0.f,0.f,0.f,0.f,0.f,0.f,
                       0.f,0.f,0.f,0.f,0.f,0.f,0.f,0.f};
    float acc0 = 3.4e38f, acc1 = 3.4e38f, acc2 = 3.4e38f, acc3 = 3.4e38f;
#pragma unroll 2
    for (int j = 0; j < TILES; ++j) {
        uint4 av = alds[aidx(j * 32 + lg, hi)];
        half8 af = *(half8*)&av;
        f32x16 c0 = __builtin_amdgcn_mfma_f32_32x32x16_f16(af, bf[0], zc, 0, 0, 0);
        acc0 = tile_min(c0, acc0);
        f32x16 c1 = __builtin_amdgcn_mfma_f32_32x32x16_f16(af, bf[1], zc, 0, 0, 0);
        acc1 = tile_min(c1, acc1);
        f32x16 c2 = __builtin_amdgcn_mfma_f32_32x32x16_f16(af, bf[2], zc, 0, 0, 0);
        acc2 = tile_min(c2, acc2);
        f32x16 c3 = __builtin_amdgcn_mfma_f32_32x32x16_f16(af, bf[3], zc, 0, 0, 0);
        acc3 = tile_min(c3, acc3);
    }

    acc0 = fminf(acc0, __shfl_xor(acc0, 32));     // merge lane halves
    acc1 = fminf(acc1, __shfl_xor(acc1, 32));
    acc2 = fminf(acc2, __shfl_xor(acc2, 32));
    acc3 = fminf(acc3, __shfl_xor(acc3, 32));

    // Per-seg partial min, agent-scope atomic stores (cross-XCD visible).
    float* pp = part + (size_t)sg * NPTS + b * NM + mbase;
    int lo = (l < 32);
    __hip_atomic_store(&pp[lo ? lg : 32 + lg], lo ? acc0 : acc1,
                       __ATOMIC_RELAXED, __HIP_MEMORY_SCOPE_AGENT);
    __hip_atomic_store(&pp[lo ? 64 + lg : 96 + lg], lo ? acc2 : acc3,
                       __ATOMIC_RELAXED, __HIP_MEMORY_SCOPE_AGENT);
    __threadfence();                              // release our stores
    __syncthreads();

    // ---- Group ticket: 16th arrival of (b,srcgrp) folds ----
    if (threadIdx.x == 0) {
        unsigned old = __hip_atomic_fetch_add(&tg[b * NSRCG + srcgrp], 1u,
                                              __ATOMIC_ACQ_REL,
                                              __HIP_MEMORY_SCOPE_AGENT);
        sfold = (old == NSEG - 1);
    }
    __syncthreads();
    if (!sfold) return;

    // ---- Phase 3 (folder): 512 cols, 16 segs each; sqrt; block sum ----
    int gbase = b * NM + srcgrp * 512;
    const float* sp = src + (size_t)b * 3 * NM;
    float dsum = 0.0f;
#pragma unroll
    for (int cc = 0; cc < 2; ++cc) {
        int c = threadIdx.x + cc * TPB;
        int gm = gbase + c;
        float v = fminf(
            __hip_atomic_load(&part[gm], __ATOMIC_RELAXED, __HIP_MEMORY_SCOPE_AGENT),
            __hip_atomic_load(&part[NPTS + gm], __ATOMIC_RELAXED, __HIP_MEMORY_SCOPE_AGENT));
#pragma unroll
        for (int s = 2; s < NSEG; s += 2) {
            float va = __hip_atomic_load(&part[(size_t)s * NPTS + gm],
                                         __ATOMIC_RELAXED, __HIP_MEMORY_SCOPE_AGENT);
            float vb = __hip_atomic_load(&part[(size_t)(s + 1) * NPTS + gm],
                                         __ATOMIC_RELAXED, __HIP_MEMORY_SCOPE_AGENT);
            v = min3(v, va, vb);
        }
        int m = srcgrp * 512 + c;
        float x = sp[m], y = sp[NM + m], z = sp[2 * NM + m];
        float a2 = fmaf(x, x, fmaf(y, y, z * z));
        dsum += sqrtf(fmaxf(a2 + v, 0.0f));
    }

    for (int off = 32; off > 0; off >>= 1) dsum += __shfl_down(dsum, off);
    if (l == 0) wsum[wv] = dsum;
    __syncthreads();

    if (threadIdx.x == 0) {
        float bs = (wsum[0] + wsum[1]) + (wsum[2] + wsum[3]);
        // Fixed-point (32.32) accumulate: integer adds are associative ->
        // deterministic regardless of block/folder order.
        unsigned long long inc = (unsigned long long)((double)bs * 4294967296.0);
        atomicAdd(sumfix, inc);
        __threadfence();                          // sum-add before ticket-add
        unsigned tk = atomicAdd(ticket, 1u);
        if (tk == NGRP - 1) {
            unsigned long long tot = atomicAdd(sumfix, 0ULL);  // coherent read
            out[0] = (float)((double)tot * (1.0 / 4294967296.0) * (1.0 / NPTS));
        }
    }
}

extern "C" void kernel_launch(void* const* d_in, const int* in_sizes, int n_in,
                              void* d_out, int out_size, void* d_ws, size_t ws_size,
                              hipStream_t stream) {
    const float* src = (const float*)d_in[0];   // [B,3,M]
    const float* dst = (const float*)d_in[1];   // [B,3,N]
    float* out = (float*)d_out;

    char* ws = (char*)d_ws;
    float* part = (float*)ws;                                        // 2 MB
    char* ctrl = ws + (size_t)NSEG * NPTS * 4;
    unsigned* tg = (unsigned*)ctrl;                                  // 256 B
    unsigned long long* sumfix = (unsigned long long*)(ctrl + 256);  // 8 B
    unsigned* ticket = (unsigned*)(ctrl + 264);                      // 4 B

    hipMemsetAsync(ctrl, 0, 272, stream);
    fused_kernel<<<NSEG * NB * NSRCG, TPB, 0, stream>>>(src, dst, part, tg,
                                                        sumfix, ticket, out);
}

// Round 15
// 28.604 us; speedup vs baseline: 3.3114x; 3.3114x over previous
//
#include <hip/hip_runtime.h>
#include <math.h>

// ChamferLoss: pc_src [B,3,M] f32, pc_dst [B,3,N] f32 -> scalar mean over (B,M)
// of min_n ||src_m - dst_n||.
//
// MFMA engine: d2p(n,m) = |d_n|^2 - 2 s_m . d_n as ONE K-column of
// v_mfma_f32_32x32x16_f16, split-f16 precision (per coord uh*sh, uh*sl,
// ul*sh with u=-2d; plus (wh,wl)*1; 11/16 K-slots; absmax 0.0 since R11).
//
// R14 -> R15: revert the fused/fence design (R14: per-block threadfence ->
// L2 writeback x1024 = 95us; bench dur ~= sum of kernel time, so R13's 27.6
// was kernel-resident, not launch overhead). Back to R13's proven 2-dispatch
// skeleton with ONE change: NSEG 16->32 (DSEG=256, TILES=8) -> grid 2048 =
// 8 blocks/CU (2x TLP to hide MFMA->min and ds_read latency; 8 KB LDS).

#define TPB 256

constexpr int NB = 4;
constexpr int NM = 8192;
constexpr int NN = 8192;
constexpr int NPTS = NB * NM;                     // 32768
constexpr int NSEG = 32;                          // dst segments
constexpr int DSEG = NN / NSEG;                   // 256 dst per segment
constexpr int TILES = DSEG / 32;                  // 8 MFMA tiles
constexpr int NSRCG = NM / 512;                   // 16 src groups (512 cols/blk)
constexpr int FIN_TPB = 128;
constexpr int NBLK_F = NPTS / FIN_TPB;            // 256 finish blocks

typedef _Float16 half8 __attribute__((ext_vector_type(8)));
typedef float f32x16 __attribute__((ext_vector_type(16)));

__device__ __forceinline__ float min3(float a, float b, float c) {
    return fminf(fminf(a, b), c);                 // -> v_min3_f32
}
__device__ __forceinline__ float tile_min(const f32x16& c, float acc) {
    float v0 = min3(c[0],  c[1],  c[2]);
    float v1 = min3(c[3],  c[4],  c[5]);
    float v2 = min3(c[6],  c[7],  c[8]);
    float v3 = min3(c[9],  c[10], c[11]);
    float v4 = min3(c[12], c[13], c[14]);
    float w0 = min3(v0, v1, c[15]);
    float w1 = min3(v2, v3, v4);
    return min3(acc, w0, w1);
}
// LDS A-frag slot for (row r, half h), 16B granules, XOR-swizzled.
__device__ __forceinline__ int aidx(int r, int h) {
    return ((r << 1) | h) ^ ((r >> 2) & 7);
}

// Kernel 1: block = (sg, b, srcgrp): 512 src cols vs one 256-dst segment.
// Phase 1: build A-frags (dst) into LDS + B-frags (src) in regs.
// Phase 2: 8 tiles x { ds_read A, 4 MFMA, 4 min-trees }. Plain partial store.
__global__ __launch_bounds__(TPB) void minseg_kernel(const float* __restrict__ src,
                                                     const float* __restrict__ dst,
                                                     float* __restrict__ part,
                                                     unsigned long long* __restrict__ sumfix,
                                                     unsigned* __restrict__ ticket) {
    __shared__ uint4 alds[DSEG * 2];              // 8 KB

    int l  = threadIdx.x & 63;
    int wv = threadIdx.x >> 6;
    int sg = blockIdx.x & (NSEG - 1);
    int b  = (blockIdx.x >> 5) & 3;
    int srcgrp = blockIdx.x >> 7;                 // 0..15

    if (blockIdx.x == 0 && threadIdx.x == 0) { *sumfix = 0ULL; *ticket = 0u; }

    // ---- Phase 1a: A-frags (dst) -> LDS, 1 row per thread ----
    const float* pd = dst + (size_t)b * 3 * NN;
    if (threadIdx.x < DSEG) {
        int r = threadIdx.x;                      // row in segment
        int n = sg * DSEG + r;
        float x = pd[n], y = pd[NN + n], z = pd[2 * NN + n];
        float ux = -2.0f * x, uy = -2.0f * y, uz = -2.0f * z;
        float w = fmaf(x, x, fmaf(y, y, z * z));
        _Float16 uhx = (_Float16)ux; _Float16 ulx = (_Float16)(ux - (float)uhx);
        _Float16 uhy = (_Float16)uy; _Float16 uly = (_Float16)(uy - (float)uhy);
        _Float16 uhz = (_Float16)uz; _Float16 ulz = (_Float16)(uz - (float)uhz);
        _Float16 wh  = (_Float16)w;  _Float16 wl  = (_Float16)(w - (float)wh);
        half8 a0 = {uhx, uhx, ulx, uhy, uhy, uly, uhz, uhz};
        half8 a1 = {ulz, wh, wl, (_Float16)0.f, (_Float16)0.f,
                    (_Float16)0.f, (_Float16)0.f, (_Float16)0.f};
        alds[aidx(r, 0)] = *(uint4*)&a0;
        alds[aidx(r, 1)] = *(uint4*)&a1;
    }

    // ---- Phase 1b: B-frags (src) in regs, 4 cols per lane ----
    int mbase = (srcgrp * 4 + wv) * 128;          // wave's 128 src cols
    int lg = l & 31;
    int hi = l >> 5;                              // 0: K0-7, 1: K8-15
    const float* ps = src + (size_t)b * 3 * NM;
    half8 bf[4];
#pragma unroll
    for (int k = 0; k < 4; ++k) {
        int c = mbase + k * 32 + lg;
        float x = ps[c], y = ps[NM + c], z = ps[2 * NM + c];
        _Float16 shx = (_Float16)x; _Float16 slx = (_Float16)(x - (float)shx);
        _Float16 shy = (_Float16)y; _Float16 sly = (_Float16)(y - (float)shy);
        _Float16 shz = (_Float16)z; _Float16 slz = (_Float16)(z - (float)shz);
        half8 b0 = {shx, slx, shx, shy, sly, shy, shz, slz};
        half8 b1 = {shz, (_Float16)1.f, (_Float16)1.f, (_Float16)0.f,
                    (_Float16)0.f, (_Float16)0.f, (_Float16)0.f, (_Float16)0.f};
        bf[k] = hi ? b1 : b0;
    }
    __syncthreads();

    // ---- Phase 2: MFMA main loop ----
    const f32x16 zc = {0.f,0.f,0.f,0.f,0.f,0.f,0.f,0.f,
                       0.f,0.f,0.f,0.f,0.f,0.f,0.f,0.f};
    float acc0 = 3.4e38f, acc1 = 3.4e38f, acc2 = 3.4e38f, acc3 = 3.4e38f;
#pragma unroll 2
    for (int j = 0; j < TILES; ++j) {
        uint4 av = alds[aidx(j * 32 + lg, hi)];
        half8 af = *(half8*)&av;
        f32x16 c0 = __builtin_amdgcn_mfma_f32_32x32x16_f16(af, bf[0], zc, 0, 0, 0);
        acc0 = tile_min(c0, acc0);
        f32x16 c1 = __builtin_amdgcn_mfma_f32_32x32x16_f16(af, bf[1], zc, 0, 0, 0);
        acc1 = tile_min(c1, acc1);
        f32x16 c2 = __builtin_amdgcn_mfma_f32_32x32x16_f16(af, bf[2], zc, 0, 0, 0);
        acc2 = tile_min(c2, acc2);
        f32x16 c3 = __builtin_amdgcn_mfma_f32_32x32x16_f16(af, bf[3], zc, 0, 0, 0);
        acc3 = tile_min(c3, acc3);
    }

    acc0 = fminf(acc0, __shfl_xor(acc0, 32));     // merge lane halves
    acc1 = fminf(acc1, __shfl_xor(acc1, 32));
    acc2 = fminf(acc2, __shfl_xor(acc2, 32));
    acc3 = fminf(acc3, __shfl_xor(acc3, 32));

    float* pp = part + (size_t)sg * NPTS + b * NM + mbase;
    int lo = (l < 32);
    pp[lo ? lg      : 32 + lg] = lo ? acc0 : acc1;   // plain stores, 1 writer
    pp[lo ? 64 + lg : 96 + lg] = lo ? acc2 : acc3;   // per cell per seg
}

// Kernel 2: per src point: min over 32 seg partials, d = sqrt(max(|s|^2+v,0));
// block tree-sum; deterministic fixed-point accumulate; last block writes out.
__global__ __launch_bounds__(FIN_TPB) void finish_kernel(const float* __restrict__ src,
                                                         const float* __restrict__ part,
                                                         unsigned long long* __restrict__ sumfix,
                                                         unsigned* __restrict__ ticket,
                                                         float* __restrict__ out) {
    int gm = blockIdx.x * FIN_TPB + threadIdx.x;
    int b = gm / NM, m = gm % NM;

    float v = fminf(part[gm], part[NPTS + gm]);
#pragma unroll
    for (int s = 2; s < NSEG; s += 2)
        v = min3(v, part[(size_t)s * NPTS + gm], part[(size_t)(s + 1) * NPTS + gm]);

    const float* sp = src + (size_t)b * 3 * NM;
    float x = sp[m], y = sp[NM + m], z = sp[2 * NM + m];
    float a2 = fmaf(x, x, fmaf(y, y, z * z));
    float d = sqrtf(fmaxf(a2 + v, 0.0f));

    for (int off = 32; off > 0; off >>= 1) d += __shfl_down(d, off);
    __shared__ float wsum[2];
    int lane = threadIdx.x & 63, w = threadIdx.x >> 6;
    if (lane == 0) wsum[w] = d;
    __syncthreads();

    if (threadIdx.x == 0) {
        float bs = wsum[0] + wsum[1];
        // Fixed-point (32.32) accumulate: integer adds are associative ->
        // deterministic regardless of block order.
        unsigned long long inc = (unsigned long long)((double)bs * 4294967296.0);
        atomicAdd(sumfix, inc);
        __threadfence();                          // sum-add before ticket-add
        unsigned tk = atomicAdd(ticket, 1u);
        if (tk == NBLK_F - 1) {
            unsigned long long tot = atomicAdd(sumfix, 0ULL);  // coherent read
            out[0] = (float)((double)tot * (1.0 / 4294967296.0) * (1.0 / NPTS));
        }
    }
}

extern "C" void kernel_launch(void* const* d_in, const int* in_sizes, int n_in,
                              void* d_out, int out_size, void* d_ws, size_t ws_size,
                              hipStream_t stream) {
    const float* src = (const float*)d_in[0];   // [B,3,M]
    const float* dst = (const float*)d_in[1];   // [B,3,N]
    float* out = (float*)d_out;

    char* ws = (char*)d_ws;
    float* part = (float*)ws;                                        // 4 MB
    unsigned long long* sumfix =
        (unsigned long long*)(ws + (size_t)NSEG * NPTS * 4);         // 8 B
    unsigned* ticket = (unsigned*)(ws + (size_t)NSEG * NPTS * 4 + 8);// 4 B

    minseg_kernel<<<NSEG * NB * NSRCG, TPB, 0, stream>>>(src, dst, part,
                                                         sumfix, ticket);
    finish_kernel<<<NBLK_F, FIN_TPB, 0, stream>>>(src, part, sumfix, ticket, out);
}

// Round 16
// 23.359 us; speedup vs baseline: 4.0548x; 1.2245x over previous
//
#include <hip/hip_runtime.h>
#include <math.h>

// ChamferLoss: pc_src [B,3,M] f32, pc_dst [B,3,N] f32 -> scalar mean over (B,M)
// of min_n ||src_m - dst_n||.
//
// MFMA engine: d2p(n,m) = |d_n|^2 - 2 s_m . d_n as ONE K-column of
// v_mfma_f32_32x32x16_f16, split-f16 precision (per coord uh*sh, uh*sl,
// ul*sh with u=-2d; plus (wh,wl)*1; 11/16 K-slots; absmax 0.0 since R11).
//
// R15 -> R16: ZERO device fences. R14 proved (a) dur ~= sum of kernel times
// (launch overhead ~0) and (b) per-block __threadfence is ruinously expensive
// (1024 fences -> 95us). The ticket/fixed-point epilogue (fence per block,
// x256) has polluted every round since R4 -> split into fence-free stages:
// minseg (plain partial stores) + finish (fold+sqrt+block-sum -> bsums store)
// + final (1 block folds 128 sums -> scalar). Also: 4-way MFMA ILP in the
// inner loop (4 MFMAs issued back-to-back, then 4 min-trees) to break
// regalloc-forced MFMA->tree serialization (R14 showed VGPR_Count=36, i.e.
// the compiler was reusing one C-register block serially).

#define TPB 256

constexpr int NB = 4;
constexpr int NM = 8192;
constexpr int NN = 8192;
constexpr int NPTS = NB * NM;                     // 32768
constexpr int NSEG = 16;                          // dst segments
constexpr int DSEG = NN / NSEG;                   // 512 dst per segment
constexpr int TILES = DSEG / 32;                  // 16 MFMA tiles
constexpr int NSRCG = NM / 512;                   // 16 src groups (512 cols/blk)
constexpr int FIN_TPB = 256;
constexpr int NBLK_F = NPTS / FIN_TPB;            // 128 finish blocks

typedef _Float16 half8 __attribute__((ext_vector_type(8)));
typedef float f32x16 __attribute__((ext_vector_type(16)));

__device__ __forceinline__ float min3(float a, float b, float c) {
    return fminf(fminf(a, b), c);                 // -> v_min3_f32
}
__device__ __forceinline__ float tile_min(const f32x16& c, float acc) {
    float v0 = min3(c[0],  c[1],  c[2]);
    float v1 = min3(c[3],  c[4],  c[5]);
    float v2 = min3(c[6],  c[7],  c[8]);
    float v3 = min3(c[9],  c[10], c[11]);
    float v4 = min3(c[12], c[13], c[14]);
    float w0 = min3(v0, v1, c[15]);
    float w1 = min3(v2, v3, v4);
    return min3(acc, w0, w1);
}
// LDS A-frag slot for (row r, half h), 16B granules, XOR-swizzled.
__device__ __forceinline__ int aidx(int r, int h) {
    return ((r << 1) | h) ^ ((r >> 2) & 7);
}

// Kernel 1: block = (sg, b, srcgrp): 512 src cols vs one 512-dst segment.
// Phase 1: A-frags (dst) -> LDS, B-frags (src) -> regs. Phase 2: 16 tiles x
// { ds_read A, 4 MFMA back-to-back, 4 min-trees }. Plain partial store.
__global__ __launch_bounds__(TPB) void minseg_kernel(const float* __restrict__ src,
                                                     const float* __restrict__ dst,
                                                     float* __restrict__ part) {
    __shared__ uint4 alds[DSEG * 2];              // 16 KB

    int l  = threadIdx.x & 63;
    int wv = threadIdx.x >> 6;
    int sg = blockIdx.x & (NSEG - 1);
    int b  = (blockIdx.x >> 4) & 3;
    int srcgrp = blockIdx.x >> 6;                 // 0..15

    // ---- Phase 1a: A-frags (dst) -> LDS, 2 rows per thread ----
    const float* pd = dst + (size_t)b * 3 * NN;
#pragma unroll
    for (int rr = 0; rr < 2; ++rr) {
        int r = threadIdx.x + rr * TPB;           // row in segment
        int n = sg * DSEG + r;
        float x = pd[n], y = pd[NN + n], z = pd[2 * NN + n];
        float ux = -2.0f * x, uy = -2.0f * y, uz = -2.0f * z;
        float w = fmaf(x, x, fmaf(y, y, z * z));
        _Float16 uhx = (_Float16)ux; _Float16 ulx = (_Float16)(ux - (float)uhx);
        _Float16 uhy = (_Float16)uy; _Float16 uly = (_Float16)(uy - (float)uhy);
        _Float16 uhz = (_Float16)uz; _Float16 ulz = (_Float16)(uz - (float)uhz);
        _Float16 wh  = (_Float16)w;  _Float16 wl  = (_Float16)(w - (float)wh);
        half8 a0 = {uhx, uhx, ulx, uhy, uhy, uly, uhz, uhz};
        half8 a1 = {ulz, wh, wl, (_Float16)0.f, (_Float16)0.f,
                    (_Float16)0.f, (_Float16)0.f, (_Float16)0.f};
        alds[aidx(r, 0)] = *(uint4*)&a0;
        alds[aidx(r, 1)] = *(uint4*)&a1;
    }

    // ---- Phase 1b: B-frags (src) in regs, 4 cols per lane ----
    int mbase = (srcgrp * 4 + wv) * 128;          // wave's 128 src cols
    int lg = l & 31;
    int hi = l >> 5;                              // 0: K0-7, 1: K8-15
    const float* ps = src + (size_t)b * 3 * NM;
    half8 bf[4];
#pragma unroll
    for (int k = 0; k < 4; ++k) {
        int c = mbase + k * 32 + lg;
        float x = ps[c], y = ps[NM + c], z = ps[2 * NM + c];
        _Float16 shx = (_Float16)x; _Float16 slx = (_Float16)(x - (float)shx);
        _Float16 shy = (_Float16)y; _Float16 sly = (_Float16)(y - (float)shy);
        _Float16 shz = (_Float16)z; _Float16 slz = (_Float16)(z - (float)shz);
        half8 b0 = {shx, slx, shx, shy, sly, shy, shz, slz};
        half8 b1 = {shz, (_Float16)1.f, (_Float16)1.f, (_Float16)0.f,
                    (_Float16)0.f, (_Float16)0.f, (_Float16)0.f, (_Float16)0.f};
        bf[k] = hi ? b1 : b0;
    }
    __syncthreads();

    // ---- Phase 2: MFMA main loop, 4-way ILP ----
    const f32x16 zc = {0.f,0.f,0.f,0.f,0.f,0.f,0.f,0.f,
                       0.f,0.f,0.f,0.f,0.f,0.f,0.f,0.f};
    float acc0 = 3.4e38f, acc1 = 3.4e38f, acc2 = 3.4e38f, acc3 = 3.4e38f;
#pragma unroll 2
    for (int j = 0; j < TILES; ++j) {
        uint4 av = alds[aidx(j * 32 + lg, hi)];
        half8 af = *(half8*)&av;
        f32x16 c0 = __builtin_amdgcn_mfma_f32_32x32x16_f16(af, bf[0], zc, 0, 0, 0);
        f32x16 c1 = __builtin_amdgcn_mfma_f32_32x32x16_f16(af, bf[1], zc, 0, 0, 0);
        f32x16 c2 = __builtin_amdgcn_mfma_f32_32x32x16_f16(af, bf[2], zc, 0, 0, 0);
        f32x16 c3 = __builtin_amdgcn_mfma_f32_32x32x16_f16(af, bf[3], zc, 0, 0, 0);
        acc0 = tile_min(c0, acc0);
        acc1 = tile_min(c1, acc1);
        acc2 = tile_min(c2, acc2);
        acc3 = tile_min(c3, acc3);
    }

    acc0 = fminf(acc0, __shfl_xor(acc0, 32));     // merge lane halves
    acc1 = fminf(acc1, __shfl_xor(acc1, 32));
    acc2 = fminf(acc2, __shfl_xor(acc2, 32));
    acc3 = fminf(acc3, __shfl_xor(acc3, 32));

    float* pp = part + (size_t)sg * NPTS + b * NM + mbase;
    int lo = (l < 32);
    pp[lo ? lg      : 32 + lg] = lo ? acc0 : acc1;   // plain stores, 1 writer
    pp[lo ? 64 + lg : 96 + lg] = lo ? acc2 : acc3;   // per cell per seg
}

// Kernel 2: per src point: min over 16 seg partials, d = sqrt(max(|s|^2+v,0));
// block tree-sum -> bsums (plain store, NO atomics, NO fences).
__global__ __launch_bounds__(FIN_TPB) void finish_kernel(const float* __restrict__ src,
                                                         const float* __restrict__ part,
                                                         float* __restrict__ bsums) {
    int gm = blockIdx.x * FIN_TPB + threadIdx.x;
    int b = gm / NM, m = gm % NM;

    float v = fminf(part[gm], part[NPTS + gm]);
#pragma unroll
    for (int s = 2; s < NSEG; s += 2)
        v = min3(v, part[(size_t)s * NPTS + gm], part[(size_t)(s + 1) * NPTS + gm]);

    const float* sp = src + (size_t)b * 3 * NM;
    float x = sp[m], y = sp[NM + m], z = sp[2 * NM + m];
    float a2 = fmaf(x, x, fmaf(y, y, z * z));
    float d = sqrtf(fmaxf(a2 + v, 0.0f));

    for (int off = 32; off > 0; off >>= 1) d += __shfl_down(d, off);
    __shared__ float wsum[4];
    int lane = threadIdx.x & 63, w = threadIdx.x >> 6;
    if (lane == 0) wsum[w] = d;
    __syncthreads();
    if (threadIdx.x == 0)
        bsums[blockIdx.x] = (wsum[0] + wsum[1]) + (wsum[2] + wsum[3]);
}

// Kernel 3: deterministic final tree-sum of 128 block sums, scale to mean.
__global__ __launch_bounds__(TPB) void final_kernel(const float* __restrict__ bsums,
                                                    float* __restrict__ out) {
    float v = (threadIdx.x < NBLK_F) ? bsums[threadIdx.x] : 0.0f;
    for (int off = 32; off > 0; off >>= 1) v += __shfl_down(v, off);
    __shared__ float wsum[4];
    int lane = threadIdx.x & 63, w = threadIdx.x >> 6;
    if (lane == 0) wsum[w] = v;
    __syncthreads();
    if (threadIdx.x == 0)
        out[0] = ((wsum[0] + wsum[1]) + (wsum[2] + wsum[3])) * (1.0f / NPTS);
}

extern "C" void kernel_launch(void* const* d_in, const int* in_sizes, int n_in,
                              void* d_out, int out_size, void* d_ws, size_t ws_size,
                              hipStream_t stream) {
    const float* src = (const float*)d_in[0];   // [B,3,M]
    const float* dst = (const float*)d_in[1];   // [B,3,N]
    float* out = (float*)d_out;

    char* ws = (char*)d_ws;
    float* part  = (float*)ws;                                       // 2 MB
    float* bsums = (float*)(ws + (size_t)NSEG * NPTS * 4);           // 512 B

    minseg_kernel<<<NSEG * NB * NSRCG, TPB, 0, stream>>>(src, dst, part);
    finish_kernel<<<NBLK_F, FIN_TPB, 0, stream>>>(src, part, bsums);
    final_kernel<<<1, TPB, 0, stream>>>(bsums, out);
}